// Round 20
// baseline (200.893 us; speedup 1.0000x reference)
//
#include <hip/hip_runtime.h>
#include <hip/hip_bf16.h>

#define HID 128

typedef __attribute__((ext_vector_type(8))) short short8;
typedef __attribute__((ext_vector_type(4))) float f32x4;

__device__ __forceinline__ unsigned short f2bf(float f) {
    unsigned int u = __builtin_bit_cast(unsigned int, f);
    u += 0x7FFFu + ((u >> 16) & 1u);
    return (unsigned short)(u >> 16);
}
__device__ __forceinline__ float bf2f(unsigned short h) {
    unsigned int u = ((unsigned int)h) << 16;
    return __builtin_bit_cast(float, u);
}

// ---------------- fused prep: W1f | comp(Wg) | comp(Wu1) | Wu2 frags | zero cnt ----------------
__global__ void prep_all(const float* __restrict__ Wm1,
                         const float* __restrict__ Wg,  const float* __restrict__ Wu1,
                         const float* __restrict__ Wm2, const float* __restrict__ bm2,
                         const float* __restrict__ Wu2,
                         unsigned short* __restrict__ W1f,
                         unsigned short* __restrict__ WgH,  float* __restrict__ bcg,
                         unsigned short* __restrict__ Wu1H, float* __restrict__ bcu,
                         unsigned short* __restrict__ Wu2H,
                         unsigned* __restrict__ cnt, int N)
{
    int b = blockIdx.x;
    if (b < 16) {
        int t = b * 256 + threadIdx.x;
        if (t < 4096) {
            int lane = t & 63, nt = (t >> 6) & 7, ks = t >> 9;
            int kb  = ks * 32 + ((lane >> 4) << 3);
            int col = (nt << 4) + (lane & 15);
            union { unsigned short u[8]; uint4 q; } p;
            #pragma unroll
            for (int j = 0; j < 8; ++j) p.u[j] = f2bf(Wm1[(size_t)(kb + j) * 128 + col]);
            *(uint4*)(W1f + (size_t)t * 8) = p.q;
        }
    } else if (b < 272) {
        const bool isG = (b < 144);
        const float* Wtop = isG ? Wg : Wu1;
        unsigned short* Wh = isG ? WgH : Wu1H;
        float* bc = isG ? bcg : bcu;
        int lb = b - (isG ? 16 : 144);
        int t = lb * 256 + threadIdx.x;
        if (t < 32768) {
            int j = t & 7, lane = (t >> 3) & 63, nt = (t >> 9) & 7, ks = t >> 12;
            int r   = ks * 32 + ((lane >> 4) << 3) + j;
            int col = (nt << 4) + (lane & 15);
            float w;
            if (r < 128) {
                w = Wtop[(size_t)r * 128 + col];
            } else {
                const float* a = Wm2 + (size_t)(r - 128) * 128;
                float s = 0.f;
                for (int k = 0; k < 128; ++k)
                    s = fmaf(a[k], Wtop[(size_t)(128 + k) * 128 + col], s);
                w = s;
            }
            Wh[t] = f2bf(w);
        }
        if (lb == 0 && threadIdx.x < 128) {
            int jj = threadIdx.x;
            float s = 0.f;
            for (int k = 0; k < 128; ++k)
                s = fmaf(bm2[k], Wtop[(size_t)(128 + k) * 128 + jj], s);
            bc[jj] = s;
        }
    } else if (b < 280) {
        int t = (b - 272) * 256 + threadIdx.x;
        if (t < 2048) {
            int lane = t & 63, nt = (t >> 6) & 7, ks = t >> 9;
            int kb  = ks * 32 + ((lane >> 4) << 3);
            int col = (nt << 4) + (lane & 15);
            union { unsigned short u[8]; uint4 q; } p;
            #pragma unroll
            for (int j = 0; j < 8; ++j) p.u[j] = f2bf(Wu2[(size_t)(kb + j) * 128 + col]);
            *(uint4*)(Wu2H + (size_t)t * 8) = p.q;
        }
    } else {
        int t = (b - 280) * 256 + threadIdx.x;
        int i = t * 4;
        if (i + 3 < N) {
            *(uint4*)(cnt + i) = make_uint4(0u, 0u, 0u, 0u);
        } else {
            for (int k = 0; k < 4 && i + k < N; ++k) cnt[i + k] = 0u;
        }
    }
}

// ---------------- scan / scatter ----------------
__global__ void scan_k(const unsigned* __restrict__ cnt, unsigned* __restrict__ cur, int n) {
    __shared__ unsigned wsum[16];
    int tid = threadIdx.x, lane = tid & 63, w = tid >> 6;
    unsigned carry = 0;
    for (int base = 0; base < n; base += 4096) {
        int i = base + tid * 4;
        unsigned v0 = 0, v1 = 0, v2 = 0, v3 = 0;
        if (i + 3 < n) {
            uint4 q = *(const uint4*)(cnt + i);
            v0 = q.x; v1 = q.y; v2 = q.z; v3 = q.w;
        } else {
            if (i < n)     v0 = cnt[i];
            if (i + 1 < n) v1 = cnt[i + 1];
            if (i + 2 < n) v2 = cnt[i + 2];
            if (i + 3 < n) v3 = cnt[i + 3];
        }
        unsigned t0 = v0, t1 = t0 + v1, t2 = t1 + v2, t3 = t2 + v3;
        unsigned s = t3;
        #pragma unroll
        for (int off = 1; off < 64; off <<= 1) {
            unsigned t = __shfl_up(s, off);
            if (lane >= off) s += t;
        }
        if (lane == 63) wsum[w] = s;
        __syncthreads();
        if (tid < 16) {
            unsigned t = wsum[tid];
            #pragma unroll
            for (int off = 1; off < 16; off <<= 1) {
                unsigned u = __shfl_up(t, off);
                if (tid >= off) t += u;
            }
            wsum[tid] = t;
        }
        __syncthreads();
        unsigned woff = (w == 0) ? 0u : wsum[w - 1];
        unsigned excl = carry + woff + (s - t3);
        if (i < n)     cur[i]     = excl;
        if (i + 1 < n) cur[i + 1] = excl + t0;
        if (i + 2 < n) cur[i + 2] = excl + t1;
        if (i + 3 < n) cur[i + 3] = excl + t2;
        unsigned tot = wsum[15];
        __syncthreads();
        carry += tot;
    }
}

__global__ void scatter_k(const int* __restrict__ ei, const float* __restrict__ ea,
                          unsigned* __restrict__ cur, uint4* __restrict__ rec, int E) {
    int e = blockIdx.x * 256 + threadIdx.x;
    if (e >= E) return;
    int d = ei[E + e];
    unsigned pos = atomicAdd(&cur[d], 1u);
    uint4 r;
    r.x = (unsigned)ei[e];
    r.y = __builtin_bit_cast(unsigned, ea[(size_t)e * 3 + 0]);
    r.z = __builtin_bit_cast(unsigned, ea[(size_t)e * 3 + 1]);
    r.w = __builtin_bit_cast(unsigned, ea[(size_t)e * 3 + 2]);
    rec[pos] = r;
}

// ---------------- S1/T GEMM with fused degree-histogram ----------------
__global__ __launch_bounds__(256, 2)
void s1t_hist_k(const float* __restrict__ x, const unsigned short* __restrict__ W1f,
                unsigned short* __restrict__ S1b, unsigned short* __restrict__ Tb, int N,
                const int* __restrict__ ei, unsigned* __restrict__ cnt, int E)
{
    __shared__ alignas(16) unsigned short sW[32768];
    const int tid  = threadIdx.x;

    for (int e = blockIdx.x * 256 + tid; e < E; e += gridDim.x * 256)
        atomicAdd(&cnt[ei[E + e]], 1u);

    for (int i = tid; i < 4096; i += 256)
        ((uint4*)sW)[i] = ((const uint4*)W1f)[i];
    __syncthreads();

    const int lane = tid & 63;
    const int wid  = tid >> 6;
    const int n0   = (blockIdx.x * 4 + wid) * 16;
    if (n0 >= N) return;
    const int arow = lane & 15;
    const int g4   = lane >> 4;

    int nr = n0 + arow; if (nr >= N) nr = N - 1;
    const float* px = x + (size_t)nr * 128 + g4 * 8;

    short8 af[4];
    #pragma unroll
    for (int ks = 0; ks < 4; ++ks) {
        float4 v0 = *(const float4*)(px + ks * 32);
        float4 v1 = *(const float4*)(px + ks * 32 + 4);
        float v[8] = { v0.x, v0.y, v0.z, v0.w, v1.x, v1.y, v1.z, v1.w };
        #pragma unroll
        for (int j = 0; j < 8; ++j) af[ks][j] = (short)f2bf(v[j]);
    }

    f32x4 s1[8], tt[8];
    #pragma unroll
    for (int i = 0; i < 8; ++i) { s1[i] = (f32x4)0.f; tt[i] = (f32x4)0.f; }
    #pragma unroll
    for (int ks = 0; ks < 4; ++ks) {
        #pragma unroll
        for (int nt = 0; nt < 8; ++nt) {
            short8 b1 = *(const short8*)(sW + (size_t)((ks * 8 + nt) * 64 + lane) * 8);
            short8 b2 = *(const short8*)(sW + (size_t)(((ks + 4) * 8 + nt) * 64 + lane) * 8);
            s1[nt] = __builtin_amdgcn_mfma_f32_16x16x32_bf16(af[ks], b1, s1[nt], 0, 0, 0);
            tt[nt] = __builtin_amdgcn_mfma_f32_16x16x32_bf16(af[ks], b2, tt[nt], 0, 0, 0);
        }
    }
    #pragma unroll
    for (int nt = 0; nt < 8; ++nt) {
        int col = nt * 16 + arow;
        #pragma unroll
        for (int r = 0; r < 4; ++r) {
            int node = n0 + g4 * 4 + r;
            if (node < N) {
                S1b[(size_t)node * 128 + col] = f2bf(s1[nt][r]);
                Tb [(size_t)node * 128 + col] = f2bf(tt[nt][r]);
            }
        }
    }
}

// ---------------- CSR edge kernel: chunk-of-4 unroll ----------------
__global__ __launch_bounds__(256, 8)
void csr_edge_k(const unsigned short* __restrict__ S1b, const unsigned short* __restrict__ Tb,
                const uint4* __restrict__ rec,
                const unsigned* __restrict__ cnt, const unsigned* __restrict__ cur,
                const float* __restrict__ W1tail, const float* __restrict__ bm1,
                float* __restrict__ HS, int N)
{
    const int lane = threadIdx.x & 63;
    const int wid  = threadIdx.x >> 6;
    const int gw   = blockIdx.x * 4 + wid;
    const int stride = gridDim.x * 4;
    const int c2 = lane * 2;

    const float w00 = W1tail[c2],       w01 = W1tail[c2 + 1];
    const float w10 = W1tail[128 + c2], w11 = W1tail[128 + c2 + 1];
    const float w20 = W1tail[256 + c2], w21 = W1tail[256 + c2 + 1];
    const float b0  = bm1[c2],          b1v = bm1[c2 + 1];

    for (int d = gw; d < N; d += stride) {
        int e1 = (int)cur[d];
        int c  = (int)cnt[d];
        int e0 = e1 - c;
        unsigned tv = *(const unsigned*)(Tb + (size_t)d * 128 + c2);
        float t0 = bf2f((unsigned short)(tv & 0xffff)) + b0;
        float t1 = bf2f((unsigned short)(tv >> 16))    + b1v;
        float a0 = 0.f, a1 = 0.f;

        int e = e0;
        for (; e + 4 <= e1; e += 4) {
            uint4 ra = rec[e];
            uint4 rb = rec[e + 1];
            uint4 rc = rec[e + 2];
            uint4 rd = rec[e + 3];
            unsigned sa = *(const unsigned*)(S1b + (size_t)ra.x * 128 + c2);
            unsigned sb = *(const unsigned*)(S1b + (size_t)rb.x * 128 + c2);
            unsigned sc = *(const unsigned*)(S1b + (size_t)rc.x * 128 + c2);
            unsigned sd = *(const unsigned*)(S1b + (size_t)rd.x * 128 + c2);
            {
                float h0 = bf2f((unsigned short)(sa & 0xffff)) + t0;
                float h1 = bf2f((unsigned short)(sa >> 16))    + t1;
                float x0 = __builtin_bit_cast(float, ra.y);
                float x1 = __builtin_bit_cast(float, ra.z);
                float x2 = __builtin_bit_cast(float, ra.w);
                h0 = fmaf(x0, w00, h0); h0 = fmaf(x1, w10, h0); h0 = fmaf(x2, w20, h0);
                h1 = fmaf(x0, w01, h1); h1 = fmaf(x1, w11, h1); h1 = fmaf(x2, w21, h1);
                a0 += fmaxf(h0, 0.f); a1 += fmaxf(h1, 0.f);
            }
            {
                float h0 = bf2f((unsigned short)(sb & 0xffff)) + t0;
                float h1 = bf2f((unsigned short)(sb >> 16))    + t1;
                float x0 = __builtin_bit_cast(float, rb.y);
                float x1 = __builtin_bit_cast(float, rb.z);
                float x2 = __builtin_bit_cast(float, rb.w);
                h0 = fmaf(x0, w00, h0); h0 = fmaf(x1, w10, h0); h0 = fmaf(x2, w20, h0);
                h1 = fmaf(x0, w01, h1); h1 = fmaf(x1, w11, h1); h1 = fmaf(x2, w21, h1);
                a0 += fmaxf(h0, 0.f); a1 += fmaxf(h1, 0.f);
            }
            {
                float h0 = bf2f((unsigned short)(sc & 0xffff)) + t0;
                float h1 = bf2f((unsigned short)(sc >> 16))    + t1;
                float x0 = __builtin_bit_cast(float, rc.y);
                float x1 = __builtin_bit_cast(float, rc.z);
                float x2 = __builtin_bit_cast(float, rc.w);
                h0 = fmaf(x0, w00, h0); h0 = fmaf(x1, w10, h0); h0 = fmaf(x2, w20, h0);
                h1 = fmaf(x0, w01, h1); h1 = fmaf(x1, w11, h1); h1 = fmaf(x2, w21, h1);
                a0 += fmaxf(h0, 0.f); a1 += fmaxf(h1, 0.f);
            }
            {
                float h0 = bf2f((unsigned short)(sd & 0xffff)) + t0;
                float h1 = bf2f((unsigned short)(sd >> 16))    + t1;
                float x0 = __builtin_bit_cast(float, rd.y);
                float x1 = __builtin_bit_cast(float, rd.z);
                float x2 = __builtin_bit_cast(float, rd.w);
                h0 = fmaf(x0, w00, h0); h0 = fmaf(x1, w10, h0); h0 = fmaf(x2, w20, h0);
                h1 = fmaf(x0, w01, h1); h1 = fmaf(x1, w11, h1); h1 = fmaf(x2, w21, h1);
                a0 += fmaxf(h0, 0.f); a1 += fmaxf(h1, 0.f);
            }
        }
        for (; e < e1; ++e) {
            uint4 r = rec[e];
            unsigned sv = *(const unsigned*)(S1b + (size_t)r.x * 128 + c2);
            float h0 = bf2f((unsigned short)(sv & 0xffff)) + t0;
            float h1 = bf2f((unsigned short)(sv >> 16))    + t1;
            float x0 = __builtin_bit_cast(float, r.y);
            float x1 = __builtin_bit_cast(float, r.z);
            float x2 = __builtin_bit_cast(float, r.w);
            h0 = fmaf(x0, w00, h0); h0 = fmaf(x1, w10, h0); h0 = fmaf(x2, w20, h0);
            h1 = fmaf(x0, w01, h1); h1 = fmaf(x1, w11, h1); h1 = fmaf(x2, w21, h1);
            a0 += fmaxf(h0, 0.f); a1 += fmaxf(h1, 0.f);
        }

        float2 o; o.x = a0; o.y = a1;
        *(float2*)(HS + (size_t)d * 128 + c2) = o;
    }
}

// tier-B fallback: per-edge atomics (HS pre-zeroed)
__global__ __launch_bounds__(256, 8)
void atomic_edge_k(const unsigned short* __restrict__ S1b, const unsigned short* __restrict__ Tb,
                   const int* __restrict__ ei, const float* __restrict__ ea,
                   const float* __restrict__ W1tail, const float* __restrict__ bm1,
                   float* __restrict__ HS, int E)
{
    const int lane = threadIdx.x & 63;
    const int wid  = threadIdx.x >> 6;
    const int gw   = blockIdx.x * 4 + wid;
    const int stride = gridDim.x * 4;
    const int c2 = lane * 2;

    const float w00 = W1tail[c2],       w01 = W1tail[c2 + 1];
    const float w10 = W1tail[128 + c2], w11 = W1tail[128 + c2 + 1];
    const float w20 = W1tail[256 + c2], w21 = W1tail[256 + c2 + 1];
    const float b0  = bm1[c2],          b1v = bm1[c2 + 1];

    for (int e = gw; e < E; e += stride) {
        int s = ei[e], d = ei[E + e];
        float x0 = ea[(size_t)e * 3 + 0];
        float x1 = ea[(size_t)e * 3 + 1];
        float x2 = ea[(size_t)e * 3 + 2];
        unsigned tv = *(const unsigned*)(Tb + (size_t)d * 128 + c2);
        unsigned sv = *(const unsigned*)(S1b + (size_t)s * 128 + c2);
        float h0 = bf2f((unsigned short)(sv & 0xffff)) + bf2f((unsigned short)(tv & 0xffff)) + b0;
        float h1 = bf2f((unsigned short)(sv >> 16))    + bf2f((unsigned short)(tv >> 16))    + b1v;
        h0 = fmaf(x0, w00, h0); h0 = fmaf(x1, w10, h0); h0 = fmaf(x2, w20, h0);
        h1 = fmaf(x0, w01, h1); h1 = fmaf(x1, w11, h1); h1 = fmaf(x2, w21, h1);
        unsafeAtomicAdd(HS + (size_t)d * 128 + c2,     fmaxf(h0, 0.f));
        unsafeAtomicAdd(HS + (size_t)d * 128 + c2 + 1, fmaxf(h1, 0.f));
    }
}

// ---------------- Node kernel: ping-pong staging + LDS overlay (48 KB, 3 blocks/CU) ----------
__global__ __launch_bounds__(256, 2)
void node_mfma(const float* __restrict__ x,
               const float* __restrict__ HS,
               const unsigned* __restrict__ cnt,
               const float* __restrict__ bcg, const float* __restrict__ bcu,
               const unsigned short* __restrict__ WgH,
               const unsigned short* __restrict__ Wu1H,
               const unsigned short* __restrict__ Wu2H,
               const float* __restrict__ bg, const float* __restrict__ bu1,
               const float* __restrict__ bu2,
               const float* __restrict__ gamma, const float* __restrict__ beta,
               float* __restrict__ out, int N)
{
    // gate/u1 phase: buf0 [0,16K), buf1 [16K,32K)  (8K gate + 8K u1 each)
    // after: Hs overlays [0,32K) (4 waves x 8 KB); u2 ping-pong [32K,40K) / [40K,48K)
    __shared__ alignas(16) char smem[49152];

    const int tid  = threadIdx.x;
    const int lane = tid & 63;
    const int wid  = tid >> 6;
    const int n0   = (blockIdx.x * 4 + wid) * 16;
    // NO early return: block barriers are cooperative.

    const int arow = lane & 15;
    const int g4   = lane >> 4;

    int nr = n0 + arow; if (nr >= N) nr = N - 1;
    if (nr < 0) nr = 0;
    const float* px = x  + (size_t)nr * 128 + g4 * 8;
    const float* pa = HS + (size_t)nr * 128 + g4 * 8;

    short8 ah[8], al[8];
    #pragma unroll
    for (int ks = 0; ks < 8; ++ks) {
        const float* p = (ks < 4) ? (px + ks * 32) : (pa + (ks - 4) * 32);
        float4 v0 = *(const float4*)p;
        float4 v1 = *(const float4*)(p + 4);
        float v[8] = { v0.x, v0.y, v0.z, v0.w, v1.x, v1.y, v1.z, v1.w };
        #pragma unroll
        for (int j = 0; j < 8; ++j) {
            unsigned short h = f2bf(v[j]);
            ah[ks][j] = (short)h;
            al[ks][j] = (short)f2bf(v[j] - bf2f(h));
        }
    }

    float degf[4];
    #pragma unroll
    for (int r = 0; r < 4; ++r) {
        int node = n0 + g4 * 4 + r;
        degf[r] = (node >= 0 && node < N) ? (float)cnt[node] : 0.f;
    }

    uint4* buf0 = (uint4*)smem;
    uint4* buf1 = (uint4*)(smem + 16384);

    {
        int idx = tid, idx2 = tid + 256;
        buf0[idx]        = ((const uint4*)WgH )[idx];
        buf0[idx2]       = ((const uint4*)WgH )[idx2];
        buf0[512 + idx]  = ((const uint4*)Wu1H)[idx];
        buf0[512 + idx2] = ((const uint4*)Wu1H)[idx2];
    }
    __syncthreads();

    f32x4 ga[8], ua[8];
    #pragma unroll
    for (int i = 0; i < 8; ++i) { ga[i] = (f32x4)0.f; ua[i] = (f32x4)0.f; }

    for (int ks = 0; ks < 8; ++ks) {
        const unsigned short* sB = (const unsigned short*)((ks & 1) ? buf1 : buf0);
        uint4 tg0, tg1, tu0, tu1;
        if (ks < 7) {
            int idx = tid, idx2 = tid + 256;
            tg0 = ((const uint4*)WgH )[(ks + 1) * 512 + idx];
            tg1 = ((const uint4*)WgH )[(ks + 1) * 512 + idx2];
            tu0 = ((const uint4*)Wu1H)[(ks + 1) * 512 + idx];
            tu1 = ((const uint4*)Wu1H)[(ks + 1) * 512 + idx2];
        }
        #pragma unroll
        for (int nt = 0; nt < 8; ++nt) {
            size_t o = (size_t)(nt * 64 + lane) * 8;
            short8 bh = *(const short8*)(sB + o);
            short8 uh = *(const short8*)(sB + 4096 + o);
            ga[nt] = __builtin_amdgcn_mfma_f32_16x16x32_bf16(ah[ks], bh, ga[nt], 0, 0, 0);
            ga[nt] = __builtin_amdgcn_mfma_f32_16x16x32_bf16(al[ks], bh, ga[nt], 0, 0, 0);
            ua[nt] = __builtin_amdgcn_mfma_f32_16x16x32_bf16(ah[ks], uh, ua[nt], 0, 0, 0);
            ua[nt] = __builtin_amdgcn_mfma_f32_16x16x32_bf16(al[ks], uh, ua[nt], 0, 0, 0);
        }
        if (ks < 7) {
            uint4* nb = (ks & 1) ? buf0 : buf1;
            int idx = tid, idx2 = tid + 256;
            nb[idx]        = tg0;
            nb[idx2]       = tg1;
            nb[512 + idx]  = tu0;
            nb[512 + idx2] = tu1;
        }
        __syncthreads();   // protects next-stage write AND the Hs overlay below
    }

    #pragma unroll
    for (int nt = 0; nt < 8; ++nt) {
        int col = nt * 16 + arow;
        float bgc = bcg[col], buc = bcu[col];
        #pragma unroll
        for (int r = 0; r < 4; ++r) {
            ga[nt][r] = fmaf(degf[r], bgc, ga[nt][r]);
            ua[nt][r] = fmaf(degf[r], buc, ua[nt][r]);
        }
    }

    // Hs overlays [0,32K) — safe: all weight-buffer reads completed at the final ks barrier
    char* Hw = smem + wid * 8192;
    #pragma unroll
    for (int nt = 0; nt < 8; ++nt) {
        int col = nt * 16 + arow;
        float b1 = bu1[col];
        #pragma unroll
        for (int r = 0; r < 4; ++r) {
            int row = g4 * 4 + r;
            float u = fmaxf(ua[nt][r] + b1, 0.f);
            unsigned short h = f2bf(u);
            unsigned short l = f2bf(u - bf2f(h));
            unsigned int pk = (unsigned int)h | ((unsigned int)l << 16);
            *(unsigned int*)(Hw + row * 512 + ((col * 4) ^ ((row & 15) << 4))) = pk;
        }
    }

    #pragma unroll
    for (int nt = 0; nt < 8; ++nt) {
        int col = nt * 16 + arow;
        float b = bg[col];
        #pragma unroll
        for (int r = 0; r < 4; ++r)
            ga[nt][r] = 1.f / (1.f + expf(-(ga[nt][r] + b)));
    }

    // u2 ping-pong buffers at [32K,40K) / [40K,48K)
    uint4* ubuf0 = (uint4*)(smem + 32768);
    uint4* ubuf1 = (uint4*)(smem + 40960);
    {
        int idx = tid, idx2 = tid + 256;
        ubuf0[idx]  = ((const uint4*)Wu2H)[idx];
        ubuf0[idx2] = ((const uint4*)Wu2H)[idx2];
    }
    __syncthreads();

    f32x4 u2[8];
    #pragma unroll
    for (int i = 0; i < 8; ++i) u2[i] = (f32x4)0.f;
    for (int ks = 0; ks < 4; ++ks) {
        const unsigned short* sB = (const unsigned short*)((ks & 1) ? ubuf1 : ubuf0);
        uint4 t0v, t1v;
        if (ks < 3) {
            int idx = tid, idx2 = tid + 256;
            t0v = ((const uint4*)Wu2H)[(ks + 1) * 512 + idx];
            t1v = ((const uint4*)Wu2H)[(ks + 1) * 512 + idx2];
        }
        int b0 = ks * 128 + g4 * 32;
        unsigned int q0[4], q1[4];
        *(uint4*)q0 = *(const uint4*)(Hw + arow * 512 + ( b0       ^ (arow << 4)));
        *(uint4*)q1 = *(const uint4*)(Hw + arow * 512 + ((b0 + 16) ^ (arow << 4)));
        short8 a2h, a2l;
        #pragma unroll
        for (int j = 0; j < 4; ++j) {
            a2h[j]     = (short)(q0[j] & 0xffff);
            a2l[j]     = (short)(q0[j] >> 16);
            a2h[4 + j] = (short)(q1[j] & 0xffff);
            a2l[4 + j] = (short)(q1[j] >> 16);
        }
        #pragma unroll
        for (int nt = 0; nt < 8; ++nt) {
            size_t o = (size_t)(nt * 64 + lane) * 8;
            short8 bh = *(const short8*)(sB + o);
            u2[nt] = __builtin_amdgcn_mfma_f32_16x16x32_bf16(a2h, bh, u2[nt], 0, 0, 0);
            u2[nt] = __builtin_amdgcn_mfma_f32_16x16x32_bf16(a2l, bh, u2[nt], 0, 0, 0);
        }
        if (ks < 3) {
            uint4* nb = (ks & 1) ? ubuf0 : ubuf1;
            int idx = tid, idx2 = tid + 256;
            nb[idx]  = t0v;
            nb[idx2] = t1v;
        }
        __syncthreads();
    }

    float s[4]  = {0.f, 0.f, 0.f, 0.f};
    float ss[4] = {0.f, 0.f, 0.f, 0.f};
    #pragma unroll
    for (int nt = 0; nt < 8; ++nt) {
        int col = nt * 16 + arow;
        float b2 = bu2[col];
        #pragma unroll
        for (int r = 0; r < 4; ++r) {
            int node = n0 + g4 * 4 + r;
            int nc = (node >= 0 && node < N) ? node : 0;
            float xv = x[(size_t)nc * 128 + col];
            float g  = ga[nt][r];
            float o  = g * (u2[nt][r] + b2) + (1.f - g) * xv;
            u2[nt][r] = o;
            s[r]  += o;
            ss[r] += o * o;
        }
    }
    #pragma unroll
    for (int off = 8; off >= 1; off >>= 1) {
        #pragma unroll
        for (int r = 0; r < 4; ++r) {
            s[r]  += __shfl_xor(s[r],  off);
            ss[r] += __shfl_xor(ss[r], off);
        }
    }
    float mu[4], rstd[4];
    #pragma unroll
    for (int r = 0; r < 4; ++r) {
        mu[r] = s[r] * (1.f / 128.f);
        float var = ss[r] * (1.f / 128.f) - mu[r] * mu[r];
        rstd[r] = rsqrtf(var + 1e-5f);
    }
    #pragma unroll
    for (int nt = 0; nt < 8; ++nt) {
        int col = nt * 16 + arow;
        float gm = gamma[col], bt = beta[col];
        #pragma unroll
        for (int r = 0; r < 4; ++r) {
            int node = n0 + g4 * 4 + r;
            if (node >= 0 && node < N)
                out[(size_t)node * 128 + col] = (u2[nt][r] - mu[r]) * rstd[r] * gm + bt;
        }
    }
}

extern "C" void kernel_launch(void* const* d_in, const int* in_sizes, int n_in,
                              void* d_out, int out_size, void* d_ws, size_t ws_size,
                              hipStream_t stream)
{
    const float* x    = (const float*)d_in[0];
    const int*   ei   = (const int*)  d_in[1];
    const float* ea   = (const float*)d_in[2];
    const float* Wm1  = (const float*)d_in[3];
    const float* bm1  = (const float*)d_in[4];
    const float* Wm2  = (const float*)d_in[5];
    const float* bm2  = (const float*)d_in[6];
    const float* Wg   = (const float*)d_in[7];
    const float* bg   = (const float*)d_in[8];
    const float* Wu1  = (const float*)d_in[9];
    const float* bu1  = (const float*)d_in[10];
    const float* Wu2  = (const float*)d_in[11];
    const float* bu2  = (const float*)d_in[12];
    const float* gmma = (const float*)d_in[13];
    const float* beta = (const float*)d_in[14];
    float* out = (float*)d_out;

    const int N = in_sizes[0] / HID;
    const int E = in_sizes[1] / 2;

    // workspace carve-up
    unsigned short* S1b  = (unsigned short*)d_ws;            // N*128 bf16
    unsigned short* Tb   = S1b + (size_t)N * HID;            // N*128 bf16
    float*          HS   = (float*)(Tb + (size_t)N * HID);   // N*128 f32
    unsigned short* W1f  = (unsigned short*)(HS + (size_t)N * HID); // 32768
    unsigned short* WgH  = W1f + 32768;
    unsigned short* Wu1H = WgH + 32768;
    unsigned short* Wu2H = Wu1H + 32768;
    float*          bcg  = (float*)(Wu2H + 16384);           // 128
    float*          bcu  = bcg + 128;                        // 128
    unsigned*       cnt  = (unsigned*)(bcu + 128);           // N
    unsigned*       cur  = cnt + N;                          // N
    uint4*          rec  = (uint4*)(cur + N);
    rec = (uint4*)(((size_t)rec + 15) & ~(size_t)15);
    size_t need_sort = (size_t)((char*)(rec + E) - (char*)d_ws);
    const bool tierA = (ws_size >= need_sort);

    // fused weights prep + cnt zero
    int zblocks = ((N + 3) / 4 + 255) / 256;
    prep_all<<<dim3(280 + zblocks), dim3(256), 0, stream>>>(
        Wm1, Wg, Wu1, Wm2, bm2, Wu2, W1f, WgH, bcg, Wu1H, bcu, Wu2H, cnt, N);

    // dense per-node S1/T + fused degree histogram
    s1t_hist_k<<<dim3((N + 63) / 64), dim3(256), 0, stream>>>(
        x, W1f, S1b, Tb, N, ei, cnt, E);

    if (tierA) {
        scan_k<<<dim3(1), dim3(1024), 0, stream>>>(cnt, cur, N);
        scatter_k<<<dim3((E + 255) / 256), dim3(256), 0, stream>>>(ei, ea, cur, rec, E);
        csr_edge_k<<<dim3(2048), dim3(256), 0, stream>>>(
            S1b, Tb, rec, cnt, cur, Wm1 + 256 * HID, bm1, HS, N);
    } else {
        hipMemsetAsync(HS, 0, (size_t)N * HID * sizeof(float), stream);
        atomic_edge_k<<<dim3(2048), dim3(256), 0, stream>>>(
            S1b, Tb, ei, ea, Wm1 + 256 * HID, bm1, HS, E);
    }

    node_mfma<<<dim3((N + 63) / 64), dim3(256), 0, stream>>>(
        x, HS, cnt, bcg, bcu,
        WgH, Wu1H, Wu2H,
        bg, bu1, bu2, gmma, beta, out, N);
}